// Round 8
// baseline (2998.447 us; speedup 1.0000x reference)
//
#include <hip/hip_runtime.h>
#include <cmath>

namespace {

constexpr int Dm  = 512;
constexpr int Bn  = 32;
constexpr int Lq  = 16;
constexpr int V1  = 8193;
constexpr int DFF = 2048;
constexpr int NL  = 2;
constexpr int NT  = 256;

// ---- coherent (LLC, sc1) accessors: ONLY for same-kernel cross-block data
__device__ __forceinline__ float g_ld(const float* p) {
  return __hip_atomic_load(p, __ATOMIC_RELAXED, __HIP_MEMORY_SCOPE_AGENT);
}
__device__ __forceinline__ float2 g_ld2(const float* p) {
  unsigned long long u = __hip_atomic_load((const unsigned long long*)p,
      __ATOMIC_RELAXED, __HIP_MEMORY_SCOPE_AGENT);
  float2 r;
  r.x = __uint_as_float((unsigned)u);
  r.y = __uint_as_float((unsigned)(u >> 32));
  return r;
}
__device__ __forceinline__ void g_st2(float* p, float a, float b) {
  unsigned long long u = (unsigned long long)__float_as_uint(a) |
                         ((unsigned long long)__float_as_uint(b) << 32);
  __hip_atomic_store((unsigned long long*)p, u, __ATOMIC_RELAXED,
                     __HIP_MEMORY_SCOPE_AGENT);
}

__device__ __forceinline__ float wred(float v) {
#pragma unroll
  for (int off = 32; off; off >>= 1) v += __shfl_down(v, off, 64);
  return v;
}

__device__ __forceinline__ float dot4(const float4 w, const float4 x, float a) {
  a = fmaf(w.x, x.x, a); a = fmaf(w.y, x.y, a);
  a = fmaf(w.z, x.z, a); a = fmaf(w.w, x.w, a);
  return a;
}

__device__ __forceinline__ float pe_val(int pos, int t) {
  const int j2 = (t >> 1) << 1;
  const float div = expf((float)j2 * (-9.210340371976184f / 512.0f));
  const float ang = (float)pos * div;
  return (t & 1) ? cosf(ang) : sinf(ang);
}

// spin until counter reaches n (tail blocks only; all blocks co-resident)
__device__ __forceinline__ void wait_ctr(const unsigned* c, unsigned n) {
  if (threadIdx.x == 0) {
    while (__hip_atomic_load(c, __ATOMIC_RELAXED, __HIP_MEMORY_SCOPE_AGENT) < n)
      __builtin_amdgcn_s_sleep(2);
    asm volatile("" ::: "memory");
  }
  __syncthreads();
}

__device__ __forceinline__ void block_ln(float* s, const float* __restrict__ g,
                                         const float* __restrict__ bb, float* red) {
  const int tid = (int)threadIdx.x;
  float ls = 0.f, lq = 0.f;
  for (int t = tid; t < Dm; t += NT) { const float v = s[t]; ls += v; lq += v * v; }
  ls = wred(ls); lq = wred(lq);
  const int wave = tid >> 6, lane = tid & 63;
  if (lane == 0) { red[wave] = ls; red[4 + wave] = lq; }
  __syncthreads();
  const float sum = red[0] + red[1] + red[2] + red[3];
  const float sq  = red[4] + red[5] + red[6] + red[7];
  const float mean = sum * (1.f / Dm);
  const float var  = sq * (1.f / Dm) - mean * mean;
  const float inv  = 1.f / sqrtf(var + 1e-5f);
  __syncthreads();
  for (int t = tid; t < Dm; t += NT) s[t] = (s[t] - mean) * inv * g[t] + bb[t];
}

__global__ __launch_bounds__(512) void init_bar(unsigned* bar) {
  const int i = (int)blockIdx.x * 512 + (int)threadIdx.x;
  __hip_atomic_store(bar + i, 0u, __ATOMIC_RELAXED, __HIP_MEMORY_SCOPE_AGENT);
}

__global__ __launch_bounds__(512) void src_kernel(const int* __restrict__ meanings,
    const float* __restrict__ emb, float* __restrict__ src) {
  const int b = (int)blockIdx.x, t = (int)threadIdx.x;
  float s = 0.f;
#pragma unroll
  for (int ty = 0; ty < 8; ++ty) {
    const int idx = meanings[b * 8 + ty] + ty * 32;
    s += emb[(size_t)idx * Dm + t];
  }
  src[b * Dm + t] = s;
}

__global__ __launch_bounds__(512) void embed0(const float* __restrict__ v2e,
                                              float* __restrict__ x) {
  const int b = (int)blockIdx.x, t = (int)threadIdx.x;
  x[(b << 9) + t] = v2e[(size_t)(V1 - 1) * Dm + t] + pe_val(0, t);
}

// ---- plain k-chunked partial GEMM (setup + ffn1; round-7 verified) ------
template <int KS, int Kc, int SP, bool RELU, int ROWS>
__global__ __launch_bounds__(NT) void fg_part(
    const float* __restrict__ xsrc, int xstride, int pstride,
    const float* __restrict__ W, int K, const float* __restrict__ bias,
    float* __restrict__ part, int N) {
  constexpr int QR = Kc / 4;
  constexpr int RH = ROWS / 2;
  __shared__ float smem[32 * Kc];
  const int bid = (int)blockIdx.x, tid = (int)threadIdx.x;
  const int kc = bid % KS, k0 = kc * Kc;
  for (int idx = tid; idx < 8 * Kc; idx += NT) {
    const int b = idx / QR, q = idx - b * QR;
    const float* s0 = xsrc + (size_t)b * xstride + k0 + (q << 2);
    float4 v = *(const float4*)(s0);
#pragma unroll
    for (int s = 1; s < SP; ++s) {
      const float4 u = *(const float4*)(s0 + (size_t)s * pstride);
      v.x += u.x; v.y += u.y; v.z += u.z; v.w += u.w;
    }
    if (RELU) {
      v.x = fmaxf(v.x, 0.f); v.y = fmaxf(v.y, 0.f);
      v.z = fmaxf(v.z, 0.f); v.w = fmaxf(v.w, 0.f);
    }
    *(float4*)(smem + b * Kc + ((q ^ (b & 7)) << 2)) = v;
  }
  __syncthreads();
  const int lane = tid & 63, wave = tid >> 6;
  const int bl = lane & 31, nh = lane >> 5, sw = bl & 7;
  const float* xb = smem + bl * Kc;
  const int rowjob = (bid / KS) * 4 + wave;
  const int n0 = rowjob * ROWS + nh * RH;
  const float* w = W + (size_t)n0 * K + k0;
  float a[RH];
#pragma unroll
  for (int r = 0; r < RH; ++r) a[r] = 0.f;
#pragma unroll 4
  for (int qq = 0; qq < QR; ++qq) {
    const float4 xv = *(const float4*)(xb + ((qq ^ sw) << 2));
    const float* wq = w + (qq << 2);
#pragma unroll
    for (int r = 0; r < RH; ++r)
      a[r] = dot4(*(const float4*)(wq + (size_t)r * K), xv, a[r]);
  }
  if (kc == 0) {
#pragma unroll
    for (int r = 0; r < RH; ++r) a[r] += bias[n0 + r];
  }
  float* yb = part + (size_t)kc * 32 * N + (size_t)bl * N + n0;
#pragma unroll
  for (int r = 0; r < RH; ++r) yb[r] = a[r];
}

// ---- fused: qkv partials (768 blocks) + per-b attention tail ------------
__global__ __launch_bounds__(NT) void k_qkv_attn(const float* __restrict__ x,
    const float* __restrict__ W, const float* __restrict__ bias,
    float* __restrict__ qkvp, float* __restrict__ kcl, float* __restrict__ vcl,
    float* __restrict__ aout, unsigned* ctr, int pos) {
  __shared__ float smem[2048];
  __shared__ int tkt_s;
  const int bid = (int)blockIdx.x, tid = (int)threadIdx.x;
  const int lane = tid & 63, wave = tid >> 6;
  {  // producer: Kc=64 KS=8 ROWS=4 (round-7 fg_qkv_part, sc1 partial stores)
    constexpr int Kc = 64, QR = 16;
    const int kc = bid & 7, k0 = kc << 6;
    for (int idx = tid; idx < 512; idx += NT) {
      const int b = idx / QR, q = idx - b * QR;
      const float4 v = *(const float4*)(x + (b << 9) + k0 + (q << 2));
      *(float4*)(smem + b * Kc + ((q ^ (b & 7)) << 2)) = v;
    }
    __syncthreads();
    const int bl = lane & 31, nh = lane >> 5, sw = bl & 7;
    const float* xb = smem + bl * Kc;
    const int rowjob = (bid >> 3) * 4 + wave;   // 0..383
    const int n0 = (rowjob << 2) + (nh << 1);   // 0..1535
    const float* w = W + (size_t)n0 * Dm + k0;
    float a0 = 0.f, a1 = 0.f;
#pragma unroll 4
    for (int qq = 0; qq < QR; ++qq) {
      const float4 xv = *(const float4*)(xb + ((qq ^ sw) << 2));
      const float* wq = w + (qq << 2);
      a0 = dot4(*(const float4*)(wq), xv, a0);
      a1 = dot4(*(const float4*)(wq + Dm), xv, a1);
    }
    if (kc == 0) { a0 += bias[n0]; a1 += bias[n0 + 1]; }
    const int seg = n0 >> 9;
    float* yb = qkvp + (size_t)seg * 131072 + (size_t)kc * 16384 + (bl << 9) + (n0 & 511);
    g_st2(yb, a0, a1);
  }
  __syncthreads();  // drains each wave's sc1 stores (vmcnt) before ticket
  if (tid == 0)
    tkt_s = (int)__hip_atomic_fetch_add(ctr, 1u, __ATOMIC_RELEASE, __HIP_MEMORY_SCOPE_AGENT);
  __syncthreads();
  if (tkt_s < 736) return;
  const int b = tkt_s - 736;
  wait_ctr(ctr, 768);
  // per-b attention (round-7 body; sc1 partial reads)
  float* sQ = smem; float* sK = smem + 512; float* sV = smem + 1024;
  float* sS = smem + 1536;
  const float* qp = qkvp;
  const float* kp = qkvp + 131072;
  const float* vp = qkvp + 262144;
  for (int t = tid; t < Dm; t += NT) {
    const int o = (b << 9) + t;
    float qv = 0.f, kv = 0.f, vv = 0.f;
#pragma unroll
    for (int s = 0; s < 8; ++s) {
      qv += g_ld(qp + o + s * 16384);
      kv += g_ld(kp + o + s * 16384);
      vv += g_ld(vp + o + s * 16384);
    }
    sQ[t] = qv; sK[t] = kv; sV[t] = vv;
    const int co = ((pos * Bn + b) << 9) + t;
    kcl[co] = kv; vcl[co] = vv;  // cross-dispatch consumers: plain ok
  }
  __syncthreads();
  for (int j = wave; j <= pos; j += 4) {
    float acc;
    if (j == pos) {
      acc = dot4(*(const float4*)(sK + (lane << 2)),
                 *(const float4*)(sQ + (lane << 2)), 0.f);
      acc = dot4(*(const float4*)(sK + 256 + (lane << 2)),
                 *(const float4*)(sQ + 256 + (lane << 2)), acc);
    } else {
      const float* kr = kcl + ((size_t)(j * Bn + b) << 9);
      acc = dot4(*(const float4*)(kr + (lane << 2)),
                 *(const float4*)(sQ + (lane << 2)), 0.f);
      acc = dot4(*(const float4*)(kr + 256 + (lane << 2)),
                 *(const float4*)(sQ + 256 + (lane << 2)), acc);
    }
    acc = wred(acc);
    if (lane == 0) sS[j] = acc * 0.044194173824159216f;  // 1/sqrt(512)
  }
  __syncthreads();
  if (tid == 0) {
    float m = -1e30f;
    for (int j = 0; j <= pos; ++j) m = fmaxf(m, sS[j]);
    float s = 0.f;
    for (int j = 0; j <= pos; ++j) { const float e = expf(sS[j] - m); sS[j] = e; s += e; }
    const float inv = 1.f / s;
    for (int j = 0; j <= pos; ++j) sS[j] *= inv;
  }
  __syncthreads();
  for (int t = tid; t < Dm; t += NT) {
    float acc = sS[pos] * sV[t];
    for (int j = 0; j < pos; ++j) acc += sS[j] * vcl[((size_t)(j * Bn + b) << 9) + t];
    aout[(b << 9) + t] = acc;
  }
}

// ---- fused: saout partials (512 blocks) + per-b ln12 tail ---------------
__global__ __launch_bounds__(NT) void k_saout_ln12(const float* __restrict__ aout,
    const float* __restrict__ W, const float* __restrict__ bias,
    float* __restrict__ sop, float* __restrict__ x,
    const float* __restrict__ caCp,
    const float* __restrict__ g1, const float* __restrict__ b1,
    const float* __restrict__ g2, const float* __restrict__ b2,
    unsigned* ctr) {
  __shared__ float smem[1024];
  __shared__ float red_s[8];
  __shared__ int tkt_s;
  const int bid = (int)blockIdx.x, tid = (int)threadIdx.x;
  const int lane = tid & 63, wave = tid >> 6;
  {  // producer: KS=16 Kc=32 ROWS=4
    constexpr int Kc = 32, QR = 8;
    const int kc = bid & 15, k0 = kc << 5;
    for (int idx = tid; idx < 256; idx += NT) {
      const int b = idx / QR, q = idx - b * QR;
      const float4 v = *(const float4*)(aout + (b << 9) + k0 + (q << 2));
      *(float4*)(smem + b * Kc + ((q ^ (b & 7)) << 2)) = v;
    }
    __syncthreads();
    const int bl = lane & 31, nh = lane >> 5, sw = bl & 7;
    const float* xb = smem + bl * Kc;
    const int rowjob = (bid >> 4) * 4 + wave;  // 0..127
    const int n0 = (rowjob << 2) + (nh << 1);  // 0..510
    const float* w = W + (size_t)n0 * Dm + k0;
    float a0 = 0.f, a1 = 0.f;
#pragma unroll
    for (int qq = 0; qq < QR; ++qq) {
      const float4 xv = *(const float4*)(xb + ((qq ^ sw) << 2));
      const float* wq = w + (qq << 2);
      a0 = dot4(*(const float4*)(wq), xv, a0);
      a1 = dot4(*(const float4*)(wq + Dm), xv, a1);
    }
    if (kc == 0) { a0 += bias[n0]; a1 += bias[n0 + 1]; }
    float* yb = sop + (size_t)kc * 16384 + (bl << 9) + n0;
    g_st2(yb, a0, a1);
  }
  __syncthreads();
  if (tid == 0)
    tkt_s = (int)__hip_atomic_fetch_add(ctr, 1u, __ATOMIC_RELEASE, __HIP_MEMORY_SCOPE_AGENT);
  __syncthreads();
  if (tkt_s < 480) return;
  const int b = tkt_s - 480;
  wait_ctr(ctr, 512);
  float* sR = smem;
  for (int t = tid; t < Dm; t += NT) {
    const int o = (b << 9) + t;
    float v = x[o];
#pragma unroll
    for (int s = 0; s < 16; ++s) v += g_ld(sop + o + s * 16384);
    sR[t] = v;
  }
  __syncthreads();
  block_ln(sR, g1, b1, red_s);
  __syncthreads();
  for (int t = tid; t < Dm; t += NT) {
    const int o = (b << 9) + t;
    float v = sR[t];
#pragma unroll
    for (int s = 0; s < 4; ++s) v += caCp[o + s * 16384];
    sR[t] = v;
  }
  __syncthreads();
  block_ln(sR, g2, b2, red_s);
  __syncthreads();
  for (int t = tid; t < Dm; t += NT) x[(b << 9) + t] = sR[t];
}

// ---- fused: ffn2 partials (512 blocks) + per-b ln3 tail -----------------
__global__ __launch_bounds__(NT) void k_ffn2_ln3(const float* __restrict__ h1p,
    const float* __restrict__ W, const float* __restrict__ bias,
    float* __restrict__ f2p, float* __restrict__ x,
    const float* __restrict__ g3, const float* __restrict__ b3,
    unsigned* ctr) {
  __shared__ float smem[4096];
  __shared__ float red_s[8];
  __shared__ int tkt_s;
  const int bid = (int)blockIdx.x, tid = (int)threadIdx.x;
  const int lane = tid & 63, wave = tid >> 6;
  {  // producer: KS=16 Kc=128 SP=8 relu ROWS=4 over h1 partials
    constexpr int Kc = 128, QR = 32;
    const int kc = bid & 15, k0 = kc << 7;
    for (int idx = tid; idx < 1024; idx += NT) {
      const int b = idx / QR, q = idx - b * QR;
      const float* s0 = h1p + (size_t)b * DFF + k0 + (q << 2);
      float4 v = *(const float4*)(s0);
#pragma unroll
      for (int s = 1; s < 8; ++s) {
        const float4 u = *(const float4*)(s0 + (size_t)s * 65536);
        v.x += u.x; v.y += u.y; v.z += u.z; v.w += u.w;
      }
      v.x = fmaxf(v.x, 0.f); v.y = fmaxf(v.y, 0.f);
      v.z = fmaxf(v.z, 0.f); v.w = fmaxf(v.w, 0.f);
      *(float4*)(smem + b * Kc + ((q ^ (b & 7)) << 2)) = v;
    }
    __syncthreads();
    const int bl = lane & 31, nh = lane >> 5, sw = bl & 7;
    const float* xb = smem + bl * Kc;
    const int rowjob = (bid >> 4) * 4 + wave;  // 0..127
    const int n0 = (rowjob << 2) + (nh << 1);  // 0..510
    const float* w = W + (size_t)n0 * DFF + k0;
    float a0 = 0.f, a1 = 0.f;
#pragma unroll 4
    for (int qq = 0; qq < QR; ++qq) {
      const float4 xv = *(const float4*)(xb + ((qq ^ sw) << 2));
      const float* wq = w + (qq << 2);
      a0 = dot4(*(const float4*)(wq), xv, a0);
      a1 = dot4(*(const float4*)(wq + DFF), xv, a1);
    }
    if (kc == 0) { a0 += bias[n0]; a1 += bias[n0 + 1]; }
    float* yb = f2p + (size_t)kc * 16384 + (bl << 9) + n0;
    g_st2(yb, a0, a1);
  }
  __syncthreads();
  if (tid == 0)
    tkt_s = (int)__hip_atomic_fetch_add(ctr, 1u, __ATOMIC_RELEASE, __HIP_MEMORY_SCOPE_AGENT);
  __syncthreads();
  if (tkt_s < 480) return;
  const int b = tkt_s - 480;
  wait_ctr(ctr, 512);
  float* sR = smem;
  for (int t = tid; t < Dm; t += NT) {
    const int o = (b << 9) + t;
    float v = x[o];
#pragma unroll
    for (int s = 0; s < 16; ++s) v += g_ld(f2p + o + s * 16384);
    sR[t] = v;
  }
  __syncthreads();
  block_ln(sR, g3, b3, red_s);
  __syncthreads();
  for (int t = tid; t < Dm; t += NT) x[(b << 9) + t] = sR[t];
}

// ---- fused: logits partials (1024 blocks) + per-b argmax/embed tail -----
__global__ __launch_bounds__(NT) void k_logits_argmax(float* __restrict__ x,
    const float* __restrict__ e2v_w, const float* __restrict__ e2v_b,
    const float* __restrict__ v2e, float* __restrict__ lp,
    float* __restrict__ outLogits, float* __restrict__ outToks,
    unsigned* ctr, int i) {
  __shared__ float smem[8192];
  __shared__ int tkt_s;
  const int bid = (int)blockIdx.x, tid = (int)threadIdx.x;
  const int lane = tid & 63, wave = tid >> 6;
  {  // producer: KS=2 Kc=256 ROWS=4
    constexpr int Kc = 256, QR = 64;
    const int kc = bid & 1, k0 = kc << 8;
    for (int idx = tid; idx < 2048; idx += NT) {
      const int b = idx / QR, q = idx - b * QR;
      const float4 v = *(const float4*)(x + (b << 9) + k0 + (q << 2));
      *(float4*)(smem + b * Kc + ((q ^ (b & 7)) << 2)) = v;
    }
    __syncthreads();
    const int bl = lane & 31, nh = lane >> 5, sw = bl & 7;
    const float* xb = smem + bl * Kc;
    const int rowjob = (bid >> 1) * 4 + wave;  // 0..2047
    const int n0 = (rowjob << 2) + (nh << 1);  // 0..8190
    const float* w = e2v_w + (size_t)n0 * Dm + k0;
    float a0 = 0.f, a1 = 0.f;
#pragma unroll 4
    for (int qq = 0; qq < QR; ++qq) {
      const float4 xv = *(const float4*)(xb + ((qq ^ sw) << 2));
      const float* wq = w + (qq << 2);
      a0 = dot4(*(const float4*)(wq), xv, a0);
      a1 = dot4(*(const float4*)(wq + Dm), xv, a1);
    }
    if (kc == 0) { a0 += e2v_b[n0]; a1 += e2v_b[n0 + 1]; }
    float* yb = lp + (size_t)kc * 262144 + (size_t)bl * 8192 + n0;
    g_st2(yb, a0, a1);
  }
  __syncthreads();
  if (tid == 0)
    tkt_s = (int)__hip_atomic_fetch_add(ctr, 1u, __ATOMIC_RELEASE, __HIP_MEMORY_SCOPE_AGENT);
  __syncthreads();
  if (tkt_s < 992) return;
  const int b = tkt_s - 992;
  wait_ctr(ctr, 1024);
  // tail: reuse smem for reductions
  float* red = smem;
  float* sv  = smem + 8;
  int*   si  = (int*)(smem + 8 + NT);
  float ls = 0.f;
  for (int t = tid; t < Dm; t += NT)
    ls += x[(b << 9) + t] * e2v_w[(size_t)8192 * Dm + t];
  ls = wred(ls);
  if (lane == 0) red[wave] = ls;
  __syncthreads();
  float* row = outLogits + ((size_t)i * Bn + b) * V1;
  if (tid == 0) {
    const float lg = red[0] + red[1] + red[2] + red[3] + e2v_b[8192];
    row[8192] = lg;
    red[4] = lg;
  }
  __syncthreads();
  const float lg = red[4];
  float best = -1e30f; int bi = 0;
  for (int v0 = tid * 2; v0 < 8192; v0 += NT * 2) {
    const float2 a = g_ld2(lp + (b << 13) + v0);
    const float2 c = g_ld2(lp + 262144 + (b << 13) + v0);
    const float va = a.x + c.x, vb = a.y + c.y;
    row[v0] = va; row[v0 + 1] = vb;
    if (va > best) { best = va; bi = v0; }      // ascending per-thread keeps
    if (vb > best) { best = vb; bi = v0 + 1; }  // first max on ties
  }
  sv[tid] = best; si[tid] = bi;
  __syncthreads();
  for (int off = 128; off; off >>= 1) {
    if (tid < off) {
      const float v2 = sv[tid + off]; const int i2 = si[tid + off];
      if (v2 > sv[tid] || (v2 == sv[tid] && i2 < si[tid])) { sv[tid] = v2; si[tid] = i2; }
    }
    __syncthreads();
  }
  if (tid == 0) {
    int tok = si[0];
    if (lg > sv[0]) tok = 8192;  // last index wins only on strictly greater
    outToks[i * Bn + b] = (float)tok;
    si[0] = tok;
  }
  __syncthreads();
  const int tok = si[0];
  if (i + 1 < Lq) {
    for (int t = tid; t < Dm; t += NT)
      x[(b << 9) + t] = v2e[(size_t)tok * Dm + t] + pe_val(i + 1, t);
  }
}

}  // namespace

extern "C" void kernel_launch(void* const* d_in, const int* in_sizes, int n_in,
                              void* d_out, int out_size, void* d_ws, size_t ws_size,
                              hipStream_t stream) {
  (void)in_sizes; (void)n_in; (void)out_size; (void)ws_size;
  const int*   meanings  = (const int*)d_in[0];
  const float* emb_table = (const float*)d_in[1];
  const float* v2e_w     = (const float*)d_in[2];
  const float* e2v_w     = (const float*)d_in[3];
  const float* e2v_b     = (const float*)d_in[4];
  const float* sa_qkv_w  = (const float*)d_in[5];
  const float* sa_qkv_b  = (const float*)d_in[6];
  const float* sa_out_w  = (const float*)d_in[7];
  const float* sa_out_b  = (const float*)d_in[8];
  const float* ca_qkv_w  = (const float*)d_in[9];
  const float* ca_qkv_b  = (const float*)d_in[10];
  const float* ca_out_w  = (const float*)d_in[11];
  const float* ca_out_b  = (const float*)d_in[12];
  const float* ffn_w1    = (const float*)d_in[13];
  const float* ffn_b1    = (const float*)d_in[14];
  const float* ffn_w2    = (const float*)d_in[15];
  const float* ffn_b2    = (const float*)d_in[16];
  const float* ln1_g     = (const float*)d_in[17];
  const float* ln1_b     = (const float*)d_in[18];
  const float* ln2_g     = (const float*)d_in[19];
  const float* ln2_b     = (const float*)d_in[20];
  const float* ln3_g     = (const float*)d_in[21];
  const float* ln3_b     = (const float*)d_in[22];

  float* out = (float*)d_out;            // toks [16,32] then logits [16,32,8193]
  float* outLogits = out + Lq * Bn;

  char* ws = (char*)d_ws;
  unsigned* bar = (unsigned*)ws;         // 8192 counters (32 KB)
  float* f = (float*)(ws + 32768);
  float* src  = f;  f += 16384;          // [32][512]
  float* x    = f;  f += 16384;          // [32][512]
  float* aout = f;  f += 16384;          // [32][512]
  float* caCp = f;  f += 131072;         // [NL][4][32][512]
  float* A    = f;  f += 524288;         // union: qkvp 393216 / sop 262144 /
                                         //        h1p 524288 / lp 524288
  float* f2p  = f;  f += 262144;         // [16][32][512]
  float* kcache = f; f += 524288;        // [NL][16][32][512]
  float* vcache = f;

  int cidx = 0;

  init_bar<<<16, 512, 0, stream>>>(bar);
  src_kernel<<<Bn, 512, 0, stream>>>(meanings, emb_table, src);

  // cross-attn constants (memory len 1): caCp[l] parts of Wo@(Wv src+bv)+bo
  for (int l = 0; l < NL; ++l) {
    fg_part<4, 128, 1, false, 8><<<64, NT, 0, stream>>>(src, Dm, 0,
        ca_qkv_w + ((size_t)l * 3 + 2) * Dm * Dm, Dm,
        ca_qkv_b + l * 3 * Dm + 2 * Dm, A, Dm);
    fg_part<4, 128, 4, false, 8><<<64, NT, 0, stream>>>(A, Dm, 16384,
        ca_out_w + (size_t)l * Dm * Dm, Dm,
        ca_out_b + l * Dm, caCp + (size_t)l * 65536, Dm);
  }

  embed0<<<Bn, 512, 0, stream>>>(v2e_w, x);

  for (int i = 0; i < Lq; ++i) {
    for (int l = 0; l < NL; ++l) {
      float* kcl = kcache + (size_t)l * Lq * Bn * Dm;
      float* vcl = vcache + (size_t)l * Lq * Bn * Dm;
      k_qkv_attn<<<768, NT, 0, stream>>>(x,
          sa_qkv_w + (size_t)l * 3 * Dm * Dm, sa_qkv_b + l * 3 * Dm,
          A, kcl, vcl, aout, bar + (cidx++) * 32, i);
      k_saout_ln12<<<512, NT, 0, stream>>>(aout,
          sa_out_w + (size_t)l * Dm * Dm, sa_out_b + l * Dm,
          A, x, caCp + (size_t)l * 65536,
          ln1_g + l * Dm, ln1_b + l * Dm, ln2_g + l * Dm, ln2_b + l * Dm,
          bar + (cidx++) * 32);
      fg_part<8, 64, 1, false, 4><<<1024, NT, 0, stream>>>(x, Dm, 0,
          ffn_w1 + (size_t)l * DFF * Dm, Dm, ffn_b1 + l * DFF, A, DFF);
      k_ffn2_ln3<<<512, NT, 0, stream>>>(A,
          ffn_w2 + (size_t)l * Dm * DFF, ffn_b2 + l * Dm,
          f2p, x, ln3_g + l * Dm, ln3_b + l * Dm, bar + (cidx++) * 32);
    }
    k_logits_argmax<<<1024, NT, 0, stream>>>(x, e2v_w, e2v_b, v2e_w, A,
        outLogits, out, bar + (cidx++) * 32, i);
  }
}